// Round 2
// baseline (31.012 us; speedup 1.0000x reference)
//
#include <hip/hip_runtime.h>
#include <stdint.h>

// Problem constants (from reference): B=128, L=160000, C=128. All f32/int32.
#define BB 128
#define LL 160000
#define CC 128
#define VEC_PER_ROW (LL / 4)  // 40000 float4 vectors per row; L % 4 == 0

// Wave mix: out[b, p] = (dec[b]==1 && s<=p<s+crop) ? wave[perm[b], p] : wave[b, p]
// Pure f32 copy/select -> bit-exact vs numpy reference.
__global__ __launch_bounds__(256) void cutmix_wave_kernel(
    const float* __restrict__ wave,
    const float* __restrict__ lam,
    const int* __restrict__ perm,
    const float* __restrict__ dec,
    const int* __restrict__ start,
    float* __restrict__ out)
{
    const int b = blockIdx.y;  // uniform per block -> params become scalar loads

    const float lamf = lam[b];
    // Match numpy f32 semantics: (1.0 - lam) rounds, then * L rounds, then trunc.
    // (sub feeding a mul is not an FMA-contraction pattern -> safe.)
    const float om = 1.0f - lamf;
    const int crop_len = (int)(om * (float)LL);
    const int s = start[b];
    const int e = s + crop_len;  // e <= L by construction
    const bool on = (dec[b] == 1.0f);
    const int pb = perm[b];

    const float4* __restrict__ rowA = (const float4*)(wave + (size_t)b * LL);
    const float4* __restrict__ rowB = (const float4*)(wave + (size_t)pb * LL);
    float4* __restrict__ rowO = (float4*)(out + (size_t)b * LL);

    for (int v = blockIdx.x * blockDim.x + threadIdx.x; v < VEC_PER_ROW;
         v += gridDim.x * blockDim.x) {
        const int p0 = v * 4;
        float4 val;
        if (!on || (p0 + 4) <= s || p0 >= e) {
            // fully outside crop window (or row not mixed): straight copy
            val = rowA[v];
        } else if (p0 >= s && (p0 + 4) <= e) {
            // fully inside crop window: copy from permuted row
            val = rowB[v];
        } else {
            // boundary vector (<=2 per row): per-element select
            const float4 a = rowA[v];
            const float4 bb = rowB[v];
            val.x = (p0 + 0 >= s && p0 + 0 < e) ? bb.x : a.x;
            val.y = (p0 + 1 >= s && p0 + 1 < e) ? bb.y : a.y;
            val.z = (p0 + 2 >= s && p0 + 2 < e) ? bb.z : a.z;
            val.w = (p0 + 3 >= s && p0 + 3 < e) ? bb.w : a.w;
        }
        rowO[v] = val;
    }
}

// Label mix: out[b,c] = dec*(lam*oh[b,c] + (1-lam)*oh[perm[b],c]) + (1-dec)*oh[b,c]
__global__ __launch_bounds__(256) void cutmix_label_kernel(
    const float* __restrict__ onehot,
    const float* __restrict__ lam,
    const int* __restrict__ perm,
    const float* __restrict__ dec,
    float* __restrict__ out)
{
    const int idx = blockIdx.x * blockDim.x + threadIdx.x;
    if (idx >= BB * CC) return;
    const int b = idx >> 7;   // CC == 128
    const int c = idx & 127;

    const float lamf = lam[b];
    const float decf = dec[b];
    const int pb = perm[b];

    const float oh  = onehot[b * CC + c];
    const float ohp = onehot[pb * CC + c];

    const float mix  = lamf * oh + (1.0f - lamf) * ohp;
    const float outv = decf * mix + (1.0f - decf) * oh;
    out[idx] = outv;
}

extern "C" void kernel_launch(void* const* d_in, const int* in_sizes, int n_in,
                              void* d_out, int out_size, void* d_ws, size_t ws_size,
                              hipStream_t stream) {
    // setup_inputs order: wave, onehot, lam, perm, dec, start
    const float* wave   = (const float*)d_in[0];
    const float* onehot = (const float*)d_in[1];
    const float* lam    = (const float*)d_in[2];
    const int*   perm   = (const int*)d_in[3];
    const float* dec    = (const float*)d_in[4];
    const int*   start  = (const int*)d_in[5];

    float* out_wave  = (float*)d_out;
    float* out_label = out_wave + (size_t)BB * LL;

    // Wave: one row per blockIdx.y; 40 blocks x 256 threads cover 40000
    // float4 vectors/row with ~4 grid-stride iterations. 5120 blocks total.
    dim3 grid(40, BB, 1);
    cutmix_wave_kernel<<<grid, 256, 0, stream>>>(wave, lam, perm, dec, start, out_wave);

    // Labels: 16384 elements, one thread each.
    cutmix_label_kernel<<<(BB * CC + 255) / 256, 256, 0, stream>>>(
        onehot, lam, perm, dec, out_label);
}

// Round 3
// 30.086 us; speedup vs baseline: 1.0308x; 1.0308x over previous
//
#include <hip/hip_runtime.h>
#include <stdint.h>

// Problem constants (from reference): B=128, L=160000, C=128. All f32/int32.
#define BB 128
#define LL 160000
#define CC 128
#define VEC_PER_ROW (LL / 4)   // 40000 float4 vectors per row; L % 4 == 0
#define WAVE_BLOCKS 40         // blocks per row for the wave path

// clang ext_vector so __builtin_nontemporal_store accepts it directly.
typedef float f4 __attribute__((ext_vector_type(4)));

// Fused kernel.
//  blockIdx.y = batch row b.
//  blockIdx.x < WAVE_BLOCKS : wave mix for row b (grid-stride over float4s).
//  blockIdx.x == WAVE_BLOCKS: label mix for row b (threads 0..127).
//
// wave: out[b,p] = (dec[b]==1 && s<=p<s+crop) ? wave[perm[b],p] : wave[b,p]
//   pure f32 copy/select -> bit-exact vs the numpy reference.
// label: out[b,c] = dec*(lam*oh[b,c] + (1-lam)*oh[perm[b],c]) + (1-dec)*oh[b,c]
__global__ __launch_bounds__(256) void cutmix_fused_kernel(
    const float* __restrict__ wave,
    const float* __restrict__ onehot,
    const float* __restrict__ lam,
    const int* __restrict__ perm,
    const float* __restrict__ dec,
    const int* __restrict__ start,
    float* __restrict__ out_wave,
    float* __restrict__ out_label)
{
    const int b = blockIdx.y;  // uniform per block -> params become scalar loads
    const float lamf = lam[b];
    const float decf = dec[b];
    const int pb = perm[b];

    if (blockIdx.x == WAVE_BLOCKS) {
        // ---- label path: 128 elements for row b ----
        const int c = threadIdx.x;
        if (c < CC) {
            const float oh  = onehot[b * CC + c];
            const float ohp = onehot[pb * CC + c];
            const float mix  = lamf * oh + (1.0f - lamf) * ohp;
            out_label[b * CC + c] = decf * mix + (1.0f - decf) * oh;
        }
        return;
    }

    // ---- wave path ----
    // Match numpy f32 semantics: (1.0f - lam) rounds, then * L rounds, trunc.
    // (sub feeding a mul is not an FMA-contraction pattern -> safe.)
    const int crop_len = (int)((1.0f - lamf) * (float)LL);
    const int s = start[b];
    const int e = s + crop_len;            // e <= L by construction
    const bool on = (decf == 1.0f);

    const f4* __restrict__ rowA = (const f4*)(wave + (size_t)b * LL);
    const f4* __restrict__ rowB = (const f4*)(wave + (size_t)pb * LL);
    f4* __restrict__ rowO = (f4*)(out_wave + (size_t)b * LL);

    for (int v = blockIdx.x * blockDim.x + threadIdx.x; v < VEC_PER_ROW;
         v += WAVE_BLOCKS * blockDim.x) {
        const int p0 = v * 4;
        f4 val;
        if (!on || (p0 + 4) <= s || p0 >= e) {
            val = rowA[v];                  // outside crop (or row not mixed)
        } else if (p0 >= s && (p0 + 4) <= e) {
            val = rowB[v];                  // fully inside crop
        } else {
            // boundary vector (<=2 per row): per-element select
            const f4 a = rowA[v];
            const f4 bb = rowB[v];
            val.x = (p0 + 0 >= s && p0 + 0 < e) ? bb.x : a.x;
            val.y = (p0 + 1 >= s && p0 + 1 < e) ? bb.y : a.y;
            val.z = (p0 + 2 >= s && p0 + 2 < e) ? bb.z : a.z;
            val.w = (p0 + 3 >= s && p0 + 3 < e) ? bb.w : a.w;
        }
        // Output is never re-read: nontemporal keeps L2/L3 clean so the
        // permuted-row second reads stay cache-resident.
        __builtin_nontemporal_store(val, &rowO[v]);
    }
}

extern "C" void kernel_launch(void* const* d_in, const int* in_sizes, int n_in,
                              void* d_out, int out_size, void* d_ws, size_t ws_size,
                              hipStream_t stream) {
    // setup_inputs order: wave, onehot, lam, perm, dec, start
    const float* wave   = (const float*)d_in[0];
    const float* onehot = (const float*)d_in[1];
    const float* lam    = (const float*)d_in[2];
    const int*   perm   = (const int*)d_in[3];
    const float* dec    = (const float*)d_in[4];
    const int*   start  = (const int*)d_in[5];

    float* out_wave  = (float*)d_out;
    float* out_label = out_wave + (size_t)BB * LL;

    // One fused launch: 41 x 128 blocks (40 wave slices + 1 label slice per row).
    dim3 grid(WAVE_BLOCKS + 1, BB, 1);
    cutmix_fused_kernel<<<grid, 256, 0, stream>>>(
        wave, onehot, lam, perm, dec, start, out_wave, out_label);
}

// Round 4
// 29.957 us; speedup vs baseline: 1.0352x; 1.0043x over previous
//
#include <hip/hip_runtime.h>
#include <stdint.h>

// Problem constants (from reference): B=128, L=160000, C=128. All f32/int32.
#define BB 128
#define LL 160000
#define CC 128
#define VEC_PER_ROW (LL / 4)   // 40000 float4 vectors per row; L % 4 == 0
#define WAVE_BLOCKS 40         // blocks per row for the wave path

// clang ext_vector so __builtin_nontemporal_store accepts it directly.
typedef float f4 __attribute__((ext_vector_type(4)));

// Fused kernel.
//  blockIdx.y = batch row b.
//  blockIdx.x < WAVE_BLOCKS : wave mix for row b (grid-stride over float4s).
//  blockIdx.x == WAVE_BLOCKS: label mix for row b (threads 0..127).
__global__ __launch_bounds__(256) void cutmix_fused_kernel(
    const float* __restrict__ wave,
    const float* __restrict__ onehot,
    const float* __restrict__ lam,
    const int* __restrict__ perm,
    const float* __restrict__ dec,
    const int* __restrict__ start,
    float* __restrict__ out_wave,
    float* __restrict__ out_label)
{
    const int b = blockIdx.y;  // uniform per block -> params become scalar loads
    const float lamf = lam[b];
    const float decf = dec[b];
    const int pb = perm[b];

    if (blockIdx.x == WAVE_BLOCKS) {
        // ---- label path: 128 elements for row b ----
        const int c = threadIdx.x;
        if (c < CC) {
            const float oh  = onehot[b * CC + c];
            const float ohp = onehot[pb * CC + c];
            const float mix  = lamf * oh + (1.0f - lamf) * ohp;
            out_label[b * CC + c] = decf * mix + (1.0f - decf) * oh;
        }
        return;
    }

    // ---- wave path ----
    // Match numpy f32 semantics: (1.0f - lam) rounds, then * L rounds, trunc.
    const int crop_len = (int)((1.0f - lamf) * (float)LL);
    const bool on = (decf == 1.0f);
    // Fold dec==0 into an empty window so the hot loop has no 'on' test.
    const int s = on ? start[b] : 0;
    const int e = on ? (s + crop_len) : 0;   // e <= L by construction

    const f4* __restrict__ rowA = (const f4*)(wave + (size_t)b * LL);
    const f4* __restrict__ rowB = (const f4*)(wave + (size_t)pb * LL);
    f4* __restrict__ rowO = (f4*)(out_wave + (size_t)b * LL);

    // Common path: ONE unconditional load through a selected address
    // (v_cndmask on the base pointer), so the compiler can pipeline 4
    // independent loads per thread. The straddle fix (<=2 vectors per row
    // across the whole grid) is a rare second load.
#pragma unroll 4
    for (int v = blockIdx.x * blockDim.x + threadIdx.x; v < VEC_PER_ROW;
         v += WAVE_BLOCKS * blockDim.x) {
        const int p0 = v * 4;
        const bool inside = (p0 >= s) & (p0 + 4 <= e);
        const f4* __restrict__ src = inside ? rowB : rowA;
        f4 val = src[v];
        const bool straddle = (!inside) & (p0 < e) & (p0 + 4 > s);
        if (straddle) {
            const f4 bb = rowB[v];
            val.x = (p0 + 0 >= s && p0 + 0 < e) ? bb.x : val.x;
            val.y = (p0 + 1 >= s && p0 + 1 < e) ? bb.y : val.y;
            val.z = (p0 + 2 >= s && p0 + 2 < e) ? bb.z : val.z;
            val.w = (p0 + 3 >= s && p0 + 3 < e) ? bb.w : val.w;
        }
        // Output is never re-read: nontemporal keeps cache retention low so
        // the input rows stay resident for the permuted re-reads / replays.
        __builtin_nontemporal_store(val, &rowO[v]);
    }
}

extern "C" void kernel_launch(void* const* d_in, const int* in_sizes, int n_in,
                              void* d_out, int out_size, void* d_ws, size_t ws_size,
                              hipStream_t stream) {
    // setup_inputs order: wave, onehot, lam, perm, dec, start
    const float* wave   = (const float*)d_in[0];
    const float* onehot = (const float*)d_in[1];
    const float* lam    = (const float*)d_in[2];
    const int*   perm   = (const int*)d_in[3];
    const float* dec    = (const float*)d_in[4];
    const int*   start  = (const int*)d_in[5];

    float* out_wave  = (float*)d_out;
    float* out_label = out_wave + (size_t)BB * LL;

    // One fused launch: 41 x 128 blocks (40 wave slices + 1 label slice per row).
    dim3 grid(WAVE_BLOCKS + 1, BB, 1);
    cutmix_fused_kernel<<<grid, 256, 0, stream>>>(
        wave, onehot, lam, perm, dec, start, out_wave, out_label);
}

// Round 5
// 29.391 us; speedup vs baseline: 1.0552x; 1.0193x over previous
//
#include <hip/hip_runtime.h>
#include <stdint.h>

// Problem constants (from reference): B=128, L=160000, C=128. All f32/int32.
#define BB 128
#define LL 160000
#define CC 128
#define VEC_PER_ROW (LL / 4)   // 40000 float4 vectors per row; L % 4 == 0
#define WAVE_BLOCKS 40         // blocks per row for the wave path
#define STRIDE (WAVE_BLOCKS * 256)  // 10240 threads per row
#define ITERS 4                // 4 * 10240 = 40960 >= 40000 slots per row

// clang ext_vector so __builtin_nontemporal_store accepts it directly.
typedef float f4 __attribute__((ext_vector_type(4)));

// Fused kernel.
//  blockIdx.y = batch row b.
//  blockIdx.x < WAVE_BLOCKS : wave mix for row b (4 statically-indexed
//                             vectors per thread, load-all then store-all).
//  blockIdx.x == WAVE_BLOCKS: label mix for row b (threads 0..127).
__global__ __launch_bounds__(256) void cutmix_fused_kernel(
    const float* __restrict__ wave,
    const float* __restrict__ onehot,
    const float* __restrict__ lam,
    const int* __restrict__ perm,
    const float* __restrict__ dec,
    const int* __restrict__ start,
    float* __restrict__ out_wave,
    float* __restrict__ out_label)
{
    const int b = blockIdx.y;  // uniform per block -> params become scalar loads
    const float lamf = lam[b];
    const float decf = dec[b];
    const int pb = perm[b];

    if (blockIdx.x == WAVE_BLOCKS) {
        // ---- label path: 128 elements for row b ----
        const int c = threadIdx.x;
        if (c < CC) {
            const float oh  = onehot[b * CC + c];
            const float ohp = onehot[pb * CC + c];
            const float mix  = lamf * oh + (1.0f - lamf) * ohp;
            out_label[b * CC + c] = decf * mix + (1.0f - decf) * oh;
        }
        return;
    }

    // ---- wave path ----
    // Match numpy f32 semantics: (1.0f - lam) rounds, then * L rounds, trunc.
    const int crop_len = (int)((1.0f - lamf) * (float)LL);
    const bool on = (decf == 1.0f);
    // Fold dec==0 into an empty window so the hot path has no 'on' test.
    const int s = on ? start[b] : 0;
    const int e = on ? (s + crop_len) : 0;   // e <= L by construction

    const f4* __restrict__ rowA = (const f4*)(wave + (size_t)b * LL);
    const f4* __restrict__ rowB = (const f4*)(wave + (size_t)pb * LL);
    f4* __restrict__ rowO = (f4*)(out_wave + (size_t)b * LL);

    const int base = blockIdx.x * blockDim.x + threadIdx.x;

    // Phase 1: issue ALL loads (4 outstanding global_load_dwordx4 per lane,
    // 64 B in flight) before any dependent store. Static indexing only.
    f4 v0, v1, v2, v3;
    {
        const int v = base + 0 * STRIDE;
        const bool inside = (v * 4 >= s) & (v * 4 + 4 <= e);
        if (v < VEC_PER_ROW) v0 = inside ? rowB[v] : rowA[v];
    }
    {
        const int v = base + 1 * STRIDE;
        const bool inside = (v * 4 >= s) & (v * 4 + 4 <= e);
        if (v < VEC_PER_ROW) v1 = inside ? rowB[v] : rowA[v];
    }
    {
        const int v = base + 2 * STRIDE;
        const bool inside = (v * 4 >= s) & (v * 4 + 4 <= e);
        if (v < VEC_PER_ROW) v2 = inside ? rowB[v] : rowA[v];
    }
    {
        const int v = base + 3 * STRIDE;
        const bool inside = (v * 4 >= s) & (v * 4 + 4 <= e);
        if (v < VEC_PER_ROW) v3 = inside ? rowB[v] : rowA[v];
    }

    // Phase 2: straddle fix (<=2 vectors in the whole grid) + NT stores.
#define FIX_AND_STORE(VI, I)                                                   \
    {                                                                          \
        const int v = base + (I) * STRIDE;                                     \
        if (v < VEC_PER_ROW) {                                                 \
            const int p0 = v * 4;                                              \
            const bool inside = (p0 >= s) & (p0 + 4 <= e);                     \
            const bool straddle = (!inside) & (p0 < e) & (p0 + 4 > s);         \
            if (straddle) {                                                    \
                const f4 bb = rowB[v];                                         \
                VI.x = (p0 + 0 >= s && p0 + 0 < e) ? bb.x : VI.x;              \
                VI.y = (p0 + 1 >= s && p0 + 1 < e) ? bb.y : VI.y;              \
                VI.z = (p0 + 2 >= s && p0 + 2 < e) ? bb.z : VI.z;              \
                VI.w = (p0 + 3 >= s && p0 + 3 < e) ? bb.w : VI.w;              \
            }                                                                  \
            __builtin_nontemporal_store(VI, &rowO[v]);                         \
        }                                                                      \
    }
    FIX_AND_STORE(v0, 0)
    FIX_AND_STORE(v1, 1)
    FIX_AND_STORE(v2, 2)
    FIX_AND_STORE(v3, 3)
#undef FIX_AND_STORE
}

extern "C" void kernel_launch(void* const* d_in, const int* in_sizes, int n_in,
                              void* d_out, int out_size, void* d_ws, size_t ws_size,
                              hipStream_t stream) {
    // setup_inputs order: wave, onehot, lam, perm, dec, start
    const float* wave   = (const float*)d_in[0];
    const float* onehot = (const float*)d_in[1];
    const float* lam    = (const float*)d_in[2];
    const int*   perm   = (const int*)d_in[3];
    const float* dec    = (const float*)d_in[4];
    const int*   start  = (const int*)d_in[5];

    float* out_wave  = (float*)d_out;
    float* out_label = out_wave + (size_t)BB * LL;

    // One fused launch: 41 x 128 blocks (40 wave slices + 1 label slice per row).
    dim3 grid(WAVE_BLOCKS + 1, BB, 1);
    cutmix_fused_kernel<<<grid, 256, 0, stream>>>(
        wave, onehot, lam, perm, dec, start, out_wave, out_label);
}